// Round 1
// baseline (840.826 us; speedup 1.0000x reference)
//
#include <hip/hip_runtime.h>

#define DEV __device__ __forceinline__

constexpr int Bc = 2, Tc = 128, Dc = 256, Lc = 8, Hc = 4, DH = 64, Fc = 2048;
constexpr float EPS = 1e-5f, SCALE = 0.125f;  // 1/sqrt(64)

// ---- workspace layout (float offsets) ----
constexpr int OFF_K     = 0;                          // B*T*D       frame keys
constexpr int OFF_VWOH  = OFF_K + Bc * Tc * Dc;       // B*T*H*D     per-head v@Wo partials
constexpr int OFF_QCLS  = OFF_VWOH + Bc * Tc * Hc * Dc; // D
constexpr int OFF_KCLS  = OFF_QCLS + Dc;              // D
constexpr int OFF_VWOHC = OFF_KCLS + Dc;              // H*D
constexpr int OFF_SC    = OFF_VWOHC + Hc * Dc;        // B*T*H       scores vs frame keys
constexpr int OFF_SCC   = OFF_SC + Bc * Tc * Hc;      // H           score vs CLS key
constexpr int OFF_X0    = OFF_SCC + 64;               // B*T*L*D     attn residual out
constexpr int NROWS     = Bc * Tc * Lc;               // 2048 candidate rows
constexpr int OFF_H2    = OFF_X0 + NROWS * Dc;        // B*T*L*D     ln2(x0)
constexpr int OFF_UP    = OFF_H2 + NROWS * Dc;        // 2*B*T*L*D   FFN partial sums (2 F-halves)
constexpr int OFF_ENC   = OFF_UP + 2 * NROWS * Dc;    // B*T*L*D     encoder CLS outputs
constexpr int OFF_Z     = OFF_ENC + NROWS * Dc;       // B*T*L       eoc logits
constexpr int OFF_LST   = OFF_Z + NROWS;              // B*T ints    chosen lengths
// total ~2.95M floats ~= 11.3 MB

DEV int imin(int a, int b) { return a < b ? a : b; }

// block = 256 threads (4 waves). red must be shared float[4].
DEV float blockReduceSum(float v, float* red) {
#pragma unroll
  for (int off = 32; off; off >>= 1) v += __shfl_down(v, off, 64);
  const int lane = threadIdx.x & 63;
  const int w = threadIdx.x >> 6;
  __syncthreads();           // protect red from previous use
  if (lane == 0) red[w] = v;
  __syncthreads();
  return red[0] + red[1] + red[2] + red[3];
}

// ---- K1: per-row LN1 + k/v projections + per-head v@Wo; q for the CLS row ----
// rows 0..B*T-1 = frames, row B*T = cls. 4 rows per block.
__global__ __launch_bounds__(256) void k_prep(
    const float* __restrict__ frames, const float* __restrict__ cls,
    const float* __restrict__ Wq, const float* __restrict__ bq,
    const float* __restrict__ Wk, const float* __restrict__ bk,
    const float* __restrict__ Wv, const float* __restrict__ bv,
    const float* __restrict__ Wo,
    const float* __restrict__ g1, const float* __restrict__ b1,
    float* __restrict__ ws) {
  __shared__ float hsm[4][Dc];
  __shared__ float vsm[4][Dc];
  __shared__ float red[4];
  const int d = threadIdx.x;
  const int r0 = blockIdx.x * 4;
  const int nr = imin(4, Bc * Tc + 1 - r0);

  for (int rr = 0; rr < nr; ++rr) {
    const int r = r0 + rr;
    const float x = (r < Bc * Tc) ? frames[r * Dc + d] : cls[d];
    const float s = blockReduceSum(x, red);
    const float m = s * (1.0f / Dc);
    const float c = x - m;
    const float var = blockReduceSum(c * c, red) * (1.0f / Dc);
    hsm[rr][d] = c * (1.0f / sqrtf(var + EPS)) * g1[d] + b1[d];
  }
  for (int rr = nr; rr < 4; ++rr) { hsm[rr][d] = 0.f; vsm[rr][d] = 0.f; }
  __syncthreads();

  float ka[4], va[4];
#pragma unroll
  for (int rr = 0; rr < 4; ++rr) { ka[rr] = bk[d]; va[rr] = bv[d]; }
  for (int c = 0; c < Dc; ++c) {
    const float wk = Wk[c * Dc + d], wv = Wv[c * Dc + d];
#pragma unroll
    for (int rr = 0; rr < 4; ++rr) {
      ka[rr] = fmaf(hsm[rr][c], wk, ka[rr]);
      va[rr] = fmaf(hsm[rr][c], wv, va[rr]);
    }
  }
  for (int rr = 0; rr < nr; ++rr) {
    const int r = r0 + rr;
    if (r < Bc * Tc) ws[OFF_K + r * Dc + d] = ka[rr];
    else             ws[OFF_KCLS + d] = ka[rr];
    vsm[rr][d] = va[rr];
  }
  __syncthreads();

  for (int hh = 0; hh < Hc; ++hh) {
    float acc[4] = {0.f, 0.f, 0.f, 0.f};
    for (int c = 0; c < DH; ++c) {
      const float wo = Wo[(hh * DH + c) * Dc + d];
#pragma unroll
      for (int rr = 0; rr < 4; ++rr) acc[rr] = fmaf(vsm[rr][hh * DH + c], wo, acc[rr]);
    }
    for (int rr = 0; rr < nr; ++rr) {
      const int r = r0 + rr;
      if (r < Bc * Tc) ws[OFF_VWOH + r * (Hc * Dc) + hh * Dc + d] = acc[rr];
      else             ws[OFF_VWOHC + hh * Dc + d] = acc[rr];
    }
  }
  // q projection only for the CLS row
  if (r0 <= Bc * Tc && Bc * Tc < r0 + nr) {
    const int rr = Bc * Tc - r0;
    float qa = bq[d];
    for (int c = 0; c < Dc; ++c) qa = fmaf(hsm[rr][c], Wq[c * Dc + d], qa);
    ws[OFF_QCLS + d] = qa;
  }
}

// ---- K2: attention scores sc[b,t,h] = scale * q_h . k_{b,t,h}, plus CLS key ----
__global__ __launch_bounds__(256) void k_scores(float* __restrict__ ws) {
  const int idx = blockIdx.x * 256 + threadIdx.x;
  if (idx < Bc * Tc * Hc) {
    const int row = idx >> 2, hh = idx & 3;
    const float* q = ws + OFF_QCLS + hh * DH;
    const float* k = ws + OFF_K + row * Dc + hh * DH;
    float s = 0.f;
    for (int c = 0; c < DH; ++c) s = fmaf(q[c], k[c], s);
    ws[OFF_SC + idx] = s * SCALE;
  } else if (idx < Bc * Tc * Hc + Hc) {
    const int hh = idx - Bc * Tc * Hc;
    const float* q = ws + OFF_QCLS + hh * DH;
    const float* k = ws + OFF_KCLS + hh * DH;
    float s = 0.f;
    for (int c = 0; c < DH; ++c) s = fmaf(q[c], k[c], s);
    ws[OFF_SCC + hh] = s * SCALE;
  }
}

// ---- K3: per (b,i): softmax per candidate length, x0 = cls + attn@Wo + bo, h2 = ln2(x0) ----
__global__ __launch_bounds__(256) void k_attn(
    const float* __restrict__ cls, const float* __restrict__ bo,
    const float* __restrict__ g2, const float* __restrict__ b2,
    float* __restrict__ ws) {
  const int wg = blockIdx.x;          // b*T + i
  const int i = wg & (Tc - 1);
  const int d = threadIdx.x;
  const int lmax = imin(Tc - i, Lc);
  __shared__ float sv[Hc][Lc + 1];
  __shared__ float aP[Lc][Hc][Lc + 1];
  __shared__ float red[4];

  if (d < Hc * (Lc + 1)) {
    const int hh = d / (Lc + 1), j = d % (Lc + 1);
    float s = 0.f;
    if (j == 0) s = ws[OFF_SCC + hh];
    else if (j - 1 < lmax) s = ws[OFF_SC + (wg + j - 1) * Hc + hh];
    sv[hh][j] = s;
  }
  __syncthreads();

  if (d < Lc * Hc) {
    const int l = (d >> 2) + 1, hh = d & 3;
    if (l <= lmax) {
      float m = -1e30f;
      for (int j = 0; j <= l; ++j) m = fmaxf(m, sv[hh][j]);
      float den = 0.f;
      for (int j = 0; j <= l; ++j) den += expf(sv[hh][j] - m);
      const float inv = 1.f / den;
      for (int j = 0; j <= l; ++j) aP[l - 1][hh][j] = expf(sv[hh][j] - m) * inv;
    }
  }
  __syncthreads();

  float x0v[Lc];
  const float base = cls[d] + bo[d];
#pragma unroll
  for (int l = 0; l < Lc; ++l) x0v[l] = base;
  for (int j = 0; j <= lmax; ++j) {
    const float* vw = (j == 0) ? (ws + OFF_VWOHC)
                               : (ws + OFF_VWOH + (wg + j - 1) * (Hc * Dc));
    for (int hh = 0; hh < Hc; ++hh) {
      const float w = vw[hh * Dc + d];
      const int lstart = (j == 0) ? 1 : j;
      for (int l = lstart; l <= lmax; ++l) x0v[l - 1] = fmaf(aP[l - 1][hh][j], w, x0v[l - 1]);
    }
  }

  for (int l = 1; l <= lmax; ++l) {
    const float x = x0v[l - 1];
    const float s = blockReduceSum(x, red);
    const float m = s * (1.f / Dc);
    const float c = x - m;
    const float var = blockReduceSum(c * c, red) * (1.f / Dc);
    const float h2 = c * (1.f / sqrtf(var + EPS)) * g2[d] + b2[d];
    const int rowc = wg * Lc + l - 1;
    ws[OFF_X0 + rowc * Dc + d] = x;
    ws[OFF_H2 + rowc * Dc + d] = h2;
  }
  for (int l = lmax + 1; l <= Lc; ++l) {
    const int rowc = wg * Lc + l - 1;
    ws[OFF_X0 + rowc * Dc + d] = 0.f;
    ws[OFF_H2 + rowc * Dc + d] = 0.f;
  }
}

// ---- K4: fused FFN GEMM pair. 16 rows x one F-half per block; t staged in LDS. ----
__global__ __launch_bounds__(256) void k_ffn(
    const float* __restrict__ W1, const float* __restrict__ b1f,
    const float* __restrict__ W2, float* __restrict__ ws) {
  const int mtile = blockIdx.x >> 1;
  const int half = blockIdx.x & 1;
  const int r0 = mtile * 16;
  const int tid = threadIdx.x;
  __shared__ float h2s[16][Dc];
  __shared__ float ts[16][Dc];
#pragma unroll
  for (int r = 0; r < 16; ++r) h2s[r][tid] = ws[OFF_H2 + (r0 + r) * Dc + tid];
  __syncthreads();

  float u[16];
#pragma unroll
  for (int r = 0; r < 16; ++r) u[r] = 0.f;

  for (int chunk = 0; chunk < 4; ++chunk) {
    const int fbase = half * 1024 + chunk * 256;
    const int f = fbase + tid;
    float t[16];
    const float bb = b1f[f];
#pragma unroll
    for (int r = 0; r < 16; ++r) t[r] = bb;
    for (int c = 0; c < Dc; ++c) {
      const float w = W1[c * Fc + f];
#pragma unroll
      for (int r = 0; r < 16; ++r) t[r] = fmaf(h2s[r][c], w, t[r]);
    }
    __syncthreads();  // previous chunk's ts reads done
#pragma unroll
    for (int r = 0; r < 16; ++r) ts[r][tid] = fmaxf(t[r], 0.f);
    __syncthreads();
    for (int ff = 0; ff < 256; ++ff) {
      const float w2 = W2[(fbase + ff) * Dc + tid];
#pragma unroll
      for (int r = 0; r < 16; ++r) u[r] = fmaf(ts[r][ff], w2, u[r]);
    }
  }
  float* up = ws + OFF_UP + half * (NROWS * Dc);
#pragma unroll
  for (int r = 0; r < 16; ++r) up[(r0 + r) * Dc + tid] = u[r];
}

// ---- K5: enc = x0 + u0 + u1 + b2f ; z = relu(enc@We1+be1)@We2 + be2 ----
__global__ __launch_bounds__(256) void k_encz(
    const float* __restrict__ We1, const float* __restrict__ be1,
    const float* __restrict__ We2, const float* __restrict__ be2,
    const float* __restrict__ b2f, float* __restrict__ ws) {
  const int r0 = blockIdx.x * 8;
  const int f = threadIdx.x;
  __shared__ float encs[8][Dc];
  __shared__ float red[4];
  const float bb = b2f[f];
#pragma unroll
  for (int r = 0; r < 8; ++r) {
    const int row = r0 + r;
    const float e = ws[OFF_X0 + row * Dc + f] + ws[OFF_UP + row * Dc + f] +
                    ws[OFF_UP + NROWS * Dc + row * Dc + f] + bb;
    ws[OFF_ENC + row * Dc + f] = e;
    encs[r][f] = e;
  }
  __syncthreads();

  float g[8];
  const float be1f = be1[f];
#pragma unroll
  for (int r = 0; r < 8; ++r) g[r] = be1f;
  for (int c = 0; c < Dc; ++c) {
    const float w = We1[c * Dc + f];
#pragma unroll
    for (int r = 0; r < 8; ++r) g[r] = fmaf(encs[r][c], w, g[r]);
  }
  const float w2 = We2[f];
#pragma unroll
  for (int r = 0; r < 8; ++r) {
    const float zp = fmaxf(g[r], 0.f) * w2;
    const float s = blockReduceSum(zp, red);
    if (f == 0) ws[OFF_Z + r0 + r] = s + be2[0];
  }
}

// ---- K6: pick lstar per (b,i): first l<=lmax with z>0, else lmax ----
__global__ __launch_bounds__(256) void k_select(float* __restrict__ ws) {
  const int tid = threadIdx.x;  // 256 = B*T
  const int i = tid & (Tc - 1);
  const int lmax = imin(Tc - i, Lc);
  const int row0 = tid * Lc;
  int ls = lmax;
  for (int l = 1; l <= lmax; ++l) {
    if (ws[OFF_Z + row0 + l - 1] > 0.f) { ls = l; break; }
  }
  ((int*)(ws + OFF_LST))[tid] = ls;
}

// ---- K7: sequential walk in LDS + emit chunks, zero-fill, counts ----
__global__ __launch_bounds__(256) void k_emit(float* __restrict__ ws, float* __restrict__ out) {
  const int b = blockIdx.x;
  const int tid = threadIdx.x;
  __shared__ int lst[Tc];
  __shared__ int path[Tc];
  __shared__ int cnt;
  const int* lsrc = (const int*)(ws + OFF_LST);
  if (tid < Tc) lst[tid] = lsrc[b * Tc + tid];
  __syncthreads();
  if (tid == 0) {
    int i = 0, s = 0;
    while (i < Tc) {
      const int l = lst[i];
      path[s] = i * Lc + l - 1;
      ++s;
      i += l;
    }
    cnt = s;
  }
  __syncthreads();
  const int c = cnt;
  for (int s = 0; s < Tc; ++s) {
    float v = 0.f;
    if (s < c) v = ws[OFF_ENC + (b * Tc * Lc + path[s]) * Dc + tid];
    out[(b * Tc + s) * Dc + tid] = v;
  }
  if (tid == 0) out[Bc * Tc * Dc + b] = (float)c;
}

extern "C" void kernel_launch(void* const* d_in, const int* in_sizes, int n_in,
                              void* d_out, int out_size, void* d_ws, size_t ws_size,
                              hipStream_t stream) {
  const float* frames = (const float*)d_in[0];
  const float* cls    = (const float*)d_in[1];
  const float* Wq     = (const float*)d_in[2];
  const float* bq     = (const float*)d_in[3];
  const float* Wk     = (const float*)d_in[4];
  const float* bk     = (const float*)d_in[5];
  const float* Wv     = (const float*)d_in[6];
  const float* bv     = (const float*)d_in[7];
  const float* Wo     = (const float*)d_in[8];
  const float* bo     = (const float*)d_in[9];
  const float* g1     = (const float*)d_in[10];
  const float* b1     = (const float*)d_in[11];
  const float* g2     = (const float*)d_in[12];
  const float* b2     = (const float*)d_in[13];
  const float* W1     = (const float*)d_in[14];
  const float* b1f    = (const float*)d_in[15];
  const float* W2     = (const float*)d_in[16];
  const float* b2f    = (const float*)d_in[17];
  const float* We1    = (const float*)d_in[18];
  const float* be1    = (const float*)d_in[19];
  const float* We2    = (const float*)d_in[20];
  const float* be2    = (const float*)d_in[21];
  float* ws = (float*)d_ws;
  float* out = (float*)d_out;

  k_prep<<<(Bc * Tc + 1 + 3) / 4, 256, 0, stream>>>(frames, cls, Wq, bq, Wk, bk, Wv, bv, Wo, g1, b1, ws);
  k_scores<<<(Bc * Tc * Hc + Hc + 255) / 256, 256, 0, stream>>>(ws);
  k_attn<<<Bc * Tc, 256, 0, stream>>>(cls, bo, g2, b2, ws);
  k_ffn<<<256, 256, 0, stream>>>(W1, b1f, W2, ws);
  k_encz<<<NROWS / 8, 256, 0, stream>>>(We1, be1, We2, be2, b2f, ws);
  k_select<<<1, 256, 0, stream>>>(ws);
  k_emit<<<Bc, 256, 0, stream>>>(ws, out);
}

// Round 2
// 265.887 us; speedup vs baseline: 3.1623x; 3.1623x over previous
//
#include <hip/hip_runtime.h>

#define DEV __device__ __forceinline__

constexpr int Bc = 2, Tc = 128, Dc = 256, Lc = 8, Hc = 4, DH = 64, Fc = 2048;
constexpr float EPS = 1e-5f, SCALE = 0.125f;  // 1/sqrt(64)

// ---- workspace layout (float offsets) ----
constexpr int OFF_K     = 0;                          // B*T*D       frame keys
constexpr int OFF_VWOH  = OFF_K + Bc * Tc * Dc;       // B*T*H*D     per-head v@Wo partials
constexpr int OFF_QCLS  = OFF_VWOH + Bc * Tc * Hc * Dc; // D
constexpr int OFF_KCLS  = OFF_QCLS + Dc;              // D
constexpr int OFF_VWOHC = OFF_KCLS + Dc;              // H*D
constexpr int OFF_SC    = OFF_VWOHC + Hc * Dc;        // B*T*H       scores vs frame keys
constexpr int OFF_SCC   = OFF_SC + Bc * Tc * Hc;      // H           score vs CLS key
constexpr int OFF_X0    = OFF_SCC + 64;               // B*T*L*D     attn residual out
constexpr int NROWS     = Bc * Tc * Lc;               // 2048 candidate rows
constexpr int OFF_H2    = OFF_X0 + NROWS * Dc;        // B*T*L*D     ln2(x0)
constexpr int OFF_UP    = OFF_H2 + NROWS * Dc;        // 2*B*T*L*D   FFN partial sums (2 F-halves)
constexpr int OFF_ENC   = OFF_UP + 2 * NROWS * Dc;    // B*T*L*D     encoder CLS outputs
constexpr int OFF_Z     = OFF_ENC + NROWS * Dc;       // B*T*L       eoc logits
constexpr int OFF_LST   = OFF_Z + NROWS;              // B*T ints    chosen lengths
// total ~2.95M floats ~= 11.8 MB

DEV int imin(int a, int b) { return a < b ? a : b; }

// block = 256 threads (4 waves). red must be shared float[4].
DEV float blockReduceSum(float v, float* red) {
#pragma unroll
  for (int off = 32; off; off >>= 1) v += __shfl_down(v, off, 64);
  const int lane = threadIdx.x & 63;
  const int w = threadIdx.x >> 6;
  __syncthreads();           // protect red from previous use
  if (lane == 0) red[w] = v;
  __syncthreads();
  return red[0] + red[1] + red[2] + red[3];
}

// ---- K1: per-row LN1 + k/v projections + per-head v@Wo; q for the CLS row ----
// rows 0..B*T-1 = frames, row B*T = cls. 4 rows per block.
__global__ __launch_bounds__(256) void k_prep(
    const float* __restrict__ frames, const float* __restrict__ cls,
    const float* __restrict__ Wq, const float* __restrict__ bq,
    const float* __restrict__ Wk, const float* __restrict__ bk,
    const float* __restrict__ Wv, const float* __restrict__ bv,
    const float* __restrict__ Wo,
    const float* __restrict__ g1, const float* __restrict__ b1,
    float* __restrict__ ws) {
  __shared__ float hsm[4][Dc];
  __shared__ float vsm[4][Dc];
  __shared__ float red[4];
  const int d = threadIdx.x;
  const int r0 = blockIdx.x * 4;
  const int nr = imin(4, Bc * Tc + 1 - r0);

  for (int rr = 0; rr < nr; ++rr) {
    const int r = r0 + rr;
    const float x = (r < Bc * Tc) ? frames[r * Dc + d] : cls[d];
    const float s = blockReduceSum(x, red);
    const float m = s * (1.0f / Dc);
    const float c = x - m;
    const float var = blockReduceSum(c * c, red) * (1.0f / Dc);
    hsm[rr][d] = c * (1.0f / sqrtf(var + EPS)) * g1[d] + b1[d];
  }
  for (int rr = nr; rr < 4; ++rr) { hsm[rr][d] = 0.f; vsm[rr][d] = 0.f; }
  __syncthreads();

  float ka[4], va[4];
#pragma unroll
  for (int rr = 0; rr < 4; ++rr) { ka[rr] = bk[d]; va[rr] = bv[d]; }
  for (int c = 0; c < Dc; ++c) {
    const float wk = Wk[c * Dc + d], wv = Wv[c * Dc + d];
#pragma unroll
    for (int rr = 0; rr < 4; ++rr) {
      ka[rr] = fmaf(hsm[rr][c], wk, ka[rr]);
      va[rr] = fmaf(hsm[rr][c], wv, va[rr]);
    }
  }
  for (int rr = 0; rr < nr; ++rr) {
    const int r = r0 + rr;
    if (r < Bc * Tc) ws[OFF_K + r * Dc + d] = ka[rr];
    else             ws[OFF_KCLS + d] = ka[rr];
    vsm[rr][d] = va[rr];
  }
  __syncthreads();

  for (int hh = 0; hh < Hc; ++hh) {
    float acc[4] = {0.f, 0.f, 0.f, 0.f};
    for (int c = 0; c < DH; ++c) {
      const float wo = Wo[(hh * DH + c) * Dc + d];
#pragma unroll
      for (int rr = 0; rr < 4; ++rr) acc[rr] = fmaf(vsm[rr][hh * DH + c], wo, acc[rr]);
    }
    for (int rr = 0; rr < nr; ++rr) {
      const int r = r0 + rr;
      if (r < Bc * Tc) ws[OFF_VWOH + r * (Hc * Dc) + hh * Dc + d] = acc[rr];
      else             ws[OFF_VWOHC + hh * Dc + d] = acc[rr];
    }
  }
  // q projection only for the CLS row
  if (r0 <= Bc * Tc && Bc * Tc < r0 + nr) {
    const int rr = Bc * Tc - r0;
    float qa = bq[d];
    for (int c = 0; c < Dc; ++c) qa = fmaf(hsm[rr][c], Wq[c * Dc + d], qa);
    ws[OFF_QCLS + d] = qa;
  }
}

// ---- K2: attention scores sc[b,t,h] = scale * q_h . k_{b,t,h}, plus CLS key ----
__global__ __launch_bounds__(256) void k_scores(float* __restrict__ ws) {
  const int idx = blockIdx.x * 256 + threadIdx.x;
  if (idx < Bc * Tc * Hc) {
    const int row = idx >> 2, hh = idx & 3;
    const float* q = ws + OFF_QCLS + hh * DH;
    const float* k = ws + OFF_K + row * Dc + hh * DH;
    float s = 0.f;
    for (int c = 0; c < DH; ++c) s = fmaf(q[c], k[c], s);
    ws[OFF_SC + idx] = s * SCALE;
  } else if (idx < Bc * Tc * Hc + Hc) {
    const int hh = idx - Bc * Tc * Hc;
    const float* q = ws + OFF_QCLS + hh * DH;
    const float* k = ws + OFF_KCLS + hh * DH;
    float s = 0.f;
    for (int c = 0; c < DH; ++c) s = fmaf(q[c], k[c], s);
    ws[OFF_SCC + hh] = s * SCALE;
  }
}

// ---- K3: per (b,i): softmax per candidate length, x0 = cls + attn@Wo + bo, h2 = ln2(x0) ----
__global__ __launch_bounds__(256) void k_attn(
    const float* __restrict__ cls, const float* __restrict__ bo,
    const float* __restrict__ g2, const float* __restrict__ b2,
    float* __restrict__ ws) {
  const int wg = blockIdx.x;          // b*T + i
  const int i = wg & (Tc - 1);
  const int d = threadIdx.x;
  const int lmax = imin(Tc - i, Lc);
  __shared__ float sv[Hc][Lc + 1];
  __shared__ float aP[Lc][Hc][Lc + 1];
  __shared__ float red[4];

  if (d < Hc * (Lc + 1)) {
    const int hh = d / (Lc + 1), j = d % (Lc + 1);
    float s = 0.f;
    if (j == 0) s = ws[OFF_SCC + hh];
    else if (j - 1 < lmax) s = ws[OFF_SC + (wg + j - 1) * Hc + hh];
    sv[hh][j] = s;
  }
  __syncthreads();

  if (d < Lc * Hc) {
    const int l = (d >> 2) + 1, hh = d & 3;
    if (l <= lmax) {
      float m = -1e30f;
      for (int j = 0; j <= l; ++j) m = fmaxf(m, sv[hh][j]);
      float den = 0.f;
      for (int j = 0; j <= l; ++j) den += expf(sv[hh][j] - m);
      const float inv = 1.f / den;
      for (int j = 0; j <= l; ++j) aP[l - 1][hh][j] = expf(sv[hh][j] - m) * inv;
    }
  }
  __syncthreads();

  float x0v[Lc];
  const float base = cls[d] + bo[d];
#pragma unroll
  for (int l = 0; l < Lc; ++l) x0v[l] = base;
  for (int j = 0; j <= lmax; ++j) {
    const float* vw = (j == 0) ? (ws + OFF_VWOHC)
                               : (ws + OFF_VWOH + (wg + j - 1) * (Hc * Dc));
    for (int hh = 0; hh < Hc; ++hh) {
      const float w = vw[hh * Dc + d];
      const int lstart = (j == 0) ? 1 : j;
      for (int l = lstart; l <= lmax; ++l) x0v[l - 1] = fmaf(aP[l - 1][hh][j], w, x0v[l - 1]);
    }
  }

  for (int l = 1; l <= lmax; ++l) {
    const float x = x0v[l - 1];
    const float s = blockReduceSum(x, red);
    const float m = s * (1.f / Dc);
    const float c = x - m;
    const float var = blockReduceSum(c * c, red) * (1.f / Dc);
    const float h2 = c * (1.f / sqrtf(var + EPS)) * g2[d] + b2[d];
    const int rowc = wg * Lc + l - 1;
    ws[OFF_X0 + rowc * Dc + d] = x;
    ws[OFF_H2 + rowc * Dc + d] = h2;
  }
  for (int l = lmax + 1; l <= Lc; ++l) {
    const int rowc = wg * Lc + l - 1;
    ws[OFF_X0 + rowc * Dc + d] = 0.f;
    ws[OFF_H2 + rowc * Dc + d] = 0.f;
  }
}

// ---- K4: fused FFN GEMM pair, register-tiled. ----
// Grid: 512 blocks = 256 row-tiles(M=8) x 2 F-halves(1024). 256 threads.
// Phase 1: T[8][1024] = relu(H2[8][256] @ W1[:,half]) — thread owns 4 f-cols,
//          float4 W1 loads, broadcast ds_read_b128 on h2s. 128 FMA / (8 LDS + 4 GLB).
// Phase 2: U[8][256] = T @ W2[half,:] — 4-way K-split across waves (wave-uniform
//          ts addresses = pure broadcast), deterministic fixed-order LDS reduce.
__global__ __launch_bounds__(256) void k_ffn(
    const float* __restrict__ W1, const float* __restrict__ b1f,
    const float* __restrict__ W2, float* __restrict__ ws) {
  const int mtile = blockIdx.x >> 1;
  const int half = blockIdx.x & 1;
  const int r0 = mtile * 8;
  const int tid = threadIdx.x;
  __shared__ float ts[8][1024];   // 32 KB
  __shared__ float aux[8192];     // 32 KB: phase1 h2s[8][256]; phase2 redbuf[4][8][256]
  float (*h2s)[Dc] = (float(*)[Dc])aux;

#pragma unroll
  for (int r = 0; r < 8; ++r) h2s[r][tid] = ws[OFF_H2 + (r0 + r) * Dc + tid];
  __syncthreads();

  // ---- phase 1 ----
  const int f4 = half * 1024 + tid * 4;
  float t[8][4];
  {
    const float4 bb = *(const float4*)&b1f[f4];
#pragma unroll
    for (int r = 0; r < 8; ++r) { t[r][0] = bb.x; t[r][1] = bb.y; t[r][2] = bb.z; t[r][3] = bb.w; }
  }
  for (int c = 0; c < Dc; c += 4) {
    float4 wv[4];
#pragma unroll
    for (int k = 0; k < 4; ++k) wv[k] = *(const float4*)&W1[(c + k) * Fc + f4];
#pragma unroll
    for (int r = 0; r < 8; ++r) {
      const float4 h = *(const float4*)&h2s[r][c];
      const float hh[4] = {h.x, h.y, h.z, h.w};
#pragma unroll
      for (int k = 0; k < 4; ++k) {
        t[r][0] = fmaf(hh[k], wv[k].x, t[r][0]);
        t[r][1] = fmaf(hh[k], wv[k].y, t[r][1]);
        t[r][2] = fmaf(hh[k], wv[k].z, t[r][2]);
        t[r][3] = fmaf(hh[k], wv[k].w, t[r][3]);
      }
    }
  }
#pragma unroll
  for (int r = 0; r < 8; ++r) {
    float4 v;
    v.x = fmaxf(t[r][0], 0.f); v.y = fmaxf(t[r][1], 0.f);
    v.z = fmaxf(t[r][2], 0.f); v.w = fmaxf(t[r][3], 0.f);
    *(float4*)&ts[r][tid * 4] = v;
  }
  __syncthreads();

  // ---- phase 2 ----
  const int d4 = (tid & 63) * 4;
  const int ky = tid >> 6;
  float u[8][4];
#pragma unroll
  for (int r = 0; r < 8; ++r) { u[r][0] = 0.f; u[r][1] = 0.f; u[r][2] = 0.f; u[r][3] = 0.f; }
  const int fb = half * 1024 + ky * 256;
  for (int ff = 0; ff < 256; ff += 4) {
    float4 wv[4];
#pragma unroll
    for (int k = 0; k < 4; ++k) wv[k] = *(const float4*)&W2[(fb + ff + k) * Dc + d4];
#pragma unroll
    for (int r = 0; r < 8; ++r) {
      const float4 h = *(const float4*)&ts[r][ky * 256 + ff];
      const float hh[4] = {h.x, h.y, h.z, h.w};
#pragma unroll
      for (int k = 0; k < 4; ++k) {
        u[r][0] = fmaf(hh[k], wv[k].x, u[r][0]);
        u[r][1] = fmaf(hh[k], wv[k].y, u[r][1]);
        u[r][2] = fmaf(hh[k], wv[k].z, u[r][2]);
        u[r][3] = fmaf(hh[k], wv[k].w, u[r][3]);
      }
    }
  }
  // write partials to redbuf[ky][r][d4..]; h2s region is dead (all reads pre-barrier-2)
#pragma unroll
  for (int r = 0; r < 8; ++r) {
    float4 v; v.x = u[r][0]; v.y = u[r][1]; v.z = u[r][2]; v.w = u[r][3];
    *(float4*)&aux[ky * 2048 + r * 256 + d4] = v;
  }
  __syncthreads();

  float* up = ws + OFF_UP + half * (NROWS * Dc);
#pragma unroll
  for (int r = 0; r < 8; ++r) {
    const float s = ((aux[0 * 2048 + r * 256 + tid] + aux[1 * 2048 + r * 256 + tid]) +
                     aux[2 * 2048 + r * 256 + tid]) + aux[3 * 2048 + r * 256 + tid];
    up[(r0 + r) * Dc + tid] = s;
  }
}

// ---- K5: enc = x0 + u0 + u1 + b2f ; z = relu(enc@We1+be1)@We2 + be2 ----
__global__ __launch_bounds__(256) void k_encz(
    const float* __restrict__ We1, const float* __restrict__ be1,
    const float* __restrict__ We2, const float* __restrict__ be2,
    const float* __restrict__ b2f, float* __restrict__ ws) {
  const int r0 = blockIdx.x * 8;
  const int f = threadIdx.x;
  __shared__ float encs[8][Dc];
  __shared__ float red[4];
  const float bb = b2f[f];
#pragma unroll
  for (int r = 0; r < 8; ++r) {
    const int row = r0 + r;
    const float e = ws[OFF_X0 + row * Dc + f] + ws[OFF_UP + row * Dc + f] +
                    ws[OFF_UP + NROWS * Dc + row * Dc + f] + bb;
    ws[OFF_ENC + row * Dc + f] = e;
    encs[r][f] = e;
  }
  __syncthreads();

  float g[8];
  const float be1f = be1[f];
#pragma unroll
  for (int r = 0; r < 8; ++r) g[r] = be1f;
  for (int c = 0; c < Dc; ++c) {
    const float w = We1[c * Dc + f];
#pragma unroll
    for (int r = 0; r < 8; ++r) g[r] = fmaf(encs[r][c], w, g[r]);
  }
  const float w2 = We2[f];
#pragma unroll
  for (int r = 0; r < 8; ++r) {
    const float zp = fmaxf(g[r], 0.f) * w2;
    const float s = blockReduceSum(zp, red);
    if (f == 0) ws[OFF_Z + r0 + r] = s + be2[0];
  }
}

// ---- K6: pick lstar per (b,i): first l<=lmax with z>0, else lmax ----
__global__ __launch_bounds__(256) void k_select(float* __restrict__ ws) {
  const int tid = threadIdx.x;  // 256 = B*T
  const int i = tid & (Tc - 1);
  const int lmax = imin(Tc - i, Lc);
  const int row0 = tid * Lc;
  int ls = lmax;
  for (int l = 1; l <= lmax; ++l) {
    if (ws[OFF_Z + row0 + l - 1] > 0.f) { ls = l; break; }
  }
  ((int*)(ws + OFF_LST))[tid] = ls;
}

// ---- K7: sequential walk in LDS + emit chunks, zero-fill, counts ----
__global__ __launch_bounds__(256) void k_emit(float* __restrict__ ws, float* __restrict__ out) {
  const int b = blockIdx.x;
  const int tid = threadIdx.x;
  __shared__ int lst[Tc];
  __shared__ int path[Tc];
  __shared__ int cnt;
  const int* lsrc = (const int*)(ws + OFF_LST);
  if (tid < Tc) lst[tid] = lsrc[b * Tc + tid];
  __syncthreads();
  if (tid == 0) {
    int i = 0, s = 0;
    while (i < Tc) {
      const int l = lst[i];
      path[s] = i * Lc + l - 1;
      ++s;
      i += l;
    }
    cnt = s;
  }
  __syncthreads();
  const int c = cnt;
  for (int s = 0; s < Tc; ++s) {
    float v = 0.f;
    if (s < c) v = ws[OFF_ENC + (b * Tc * Lc + path[s]) * Dc + tid];
    out[(b * Tc + s) * Dc + tid] = v;
  }
  if (tid == 0) out[Bc * Tc * Dc + b] = (float)c;
}

extern "C" void kernel_launch(void* const* d_in, const int* in_sizes, int n_in,
                              void* d_out, int out_size, void* d_ws, size_t ws_size,
                              hipStream_t stream) {
  const float* frames = (const float*)d_in[0];
  const float* cls    = (const float*)d_in[1];
  const float* Wq     = (const float*)d_in[2];
  const float* bq     = (const float*)d_in[3];
  const float* Wk     = (const float*)d_in[4];
  const float* bk     = (const float*)d_in[5];
  const float* Wv     = (const float*)d_in[6];
  const float* bv     = (const float*)d_in[7];
  const float* Wo     = (const float*)d_in[8];
  const float* bo     = (const float*)d_in[9];
  const float* g1     = (const float*)d_in[10];
  const float* b1     = (const float*)d_in[11];
  const float* g2     = (const float*)d_in[12];
  const float* b2     = (const float*)d_in[13];
  const float* W1     = (const float*)d_in[14];
  const float* b1f    = (const float*)d_in[15];
  const float* W2     = (const float*)d_in[16];
  const float* b2f    = (const float*)d_in[17];
  const float* We1    = (const float*)d_in[18];
  const float* be1    = (const float*)d_in[19];
  const float* We2    = (const float*)d_in[20];
  const float* be2    = (const float*)d_in[21];
  float* ws = (float*)d_ws;
  float* out = (float*)d_out;

  k_prep<<<(Bc * Tc + 1 + 3) / 4, 256, 0, stream>>>(frames, cls, Wq, bq, Wk, bk, Wv, bv, Wo, g1, b1, ws);
  k_scores<<<(Bc * Tc * Hc + Hc + 255) / 256, 256, 0, stream>>>(ws);
  k_attn<<<Bc * Tc, 256, 0, stream>>>(cls, bo, g2, b2, ws);
  k_ffn<<<512, 256, 0, stream>>>(W1, b1f, W2, ws);
  k_encz<<<NROWS / 8, 256, 0, stream>>>(We1, be1, We2, be2, b2f, ws);
  k_select<<<1, 256, 0, stream>>>(ws);
  k_emit<<<Bc, 256, 0, stream>>>(ws, out);
}

// Round 3
// 253.877 us; speedup vs baseline: 3.3119x; 1.0473x over previous
//
#include <hip/hip_runtime.h>

#define DEV __device__ __forceinline__

constexpr int Bc = 2, Tc = 128, Dc = 256, Lc = 8, Hc = 4, DH = 64, Fc = 2048;
constexpr float EPS = 1e-5f, SCALE = 0.125f;  // 1/sqrt(64)
constexpr int NROWS = Bc * Tc * Lc;           // 2048 candidate rows
constexpr int SLAB = NROWS * Dc;              // 524288 floats

// ---- workspace layout (float offsets) ----
constexpr int OFF_K     = 0;                      // B*T*D frame keys
constexpr int OFF_VWOH  = OFF_K + Bc * Tc * Dc;   // B*T*H*D per-head v@Wo partials
constexpr int OFF_QCLS  = OFF_VWOH + Bc * Tc * Hc * Dc;
constexpr int OFF_KCLS  = OFF_QCLS + Dc;
constexpr int OFF_VWOHC = OFF_KCLS + Dc;          // H*D
constexpr int OFF_X0    = OFF_VWOHC + Hc * Dc;    // B*T*L*D attn residual out; later aliased as ENC
constexpr int OFF_ENC   = OFF_X0;                 // k_encz overwrites X0 in place
constexpr int OFF_H2    = OFF_X0 + SLAB;          // B*T*L*D ln2(x0)
constexpr int OFF_UP    = OFF_H2 + SLAB;          // 4 * SLAB FFN quarter partial sums
constexpr int OFF_Z     = OFF_UP + 4 * SLAB;      // B*T*L eoc logits
// total ~3.48M floats ~= 13.9 MB

DEV int imin(int a, int b) { return a < b ? a : b; }

// block = 256 threads (4 waves). red must be shared float[4].
DEV float blockReduceSum(float v, float* red) {
#pragma unroll
  for (int off = 32; off; off >>= 1) v += __shfl_down(v, off, 64);
  const int lane = threadIdx.x & 63;
  const int w = threadIdx.x >> 6;
  __syncthreads();  // protect red from previous use
  if (lane == 0) red[w] = v;
  __syncthreads();
  return red[0] + red[1] + red[2] + red[3];
}

// ---- K1: one row per block. LN1 + k/v projections + per-head v@Wo; q for CLS row. ----
__global__ __launch_bounds__(256) void k_prep(
    const float* __restrict__ frames, const float* __restrict__ cls,
    const float* __restrict__ Wq, const float* __restrict__ bq,
    const float* __restrict__ Wk, const float* __restrict__ bk,
    const float* __restrict__ Wv, const float* __restrict__ bv,
    const float* __restrict__ Wo,
    const float* __restrict__ g1, const float* __restrict__ b1,
    float* __restrict__ ws) {
  __shared__ float hsm[Dc];
  __shared__ float vsm[Dc];
  __shared__ float red[4];
  const int d = threadIdx.x;
  const int r = blockIdx.x;  // 0..B*T-1 frames, B*T = cls

  const float x = (r < Bc * Tc) ? frames[r * Dc + d] : cls[d];
  const float s = blockReduceSum(x, red);
  const float m = s * (1.0f / Dc);
  const float c = x - m;
  const float var = blockReduceSum(c * c, red) * (1.0f / Dc);
  hsm[d] = c * (1.0f / sqrtf(var + EPS)) * g1[d] + b1[d];
  __syncthreads();

  float ka = bk[d], va = bv[d];
  for (int c2 = 0; c2 < Dc; ++c2) {
    const float h = hsm[c2];
    ka = fmaf(h, Wk[c2 * Dc + d], ka);
    va = fmaf(h, Wv[c2 * Dc + d], va);
  }
  if (r < Bc * Tc) ws[OFF_K + r * Dc + d] = ka;
  else             ws[OFF_KCLS + d] = ka;
  vsm[d] = va;
  __syncthreads();

#pragma unroll
  for (int hh = 0; hh < Hc; ++hh) {
    float acc = 0.f;
    for (int c2 = 0; c2 < DH; ++c2)
      acc = fmaf(vsm[hh * DH + c2], Wo[(hh * DH + c2) * Dc + d], acc);
    if (r < Bc * Tc) ws[OFF_VWOH + r * (Hc * Dc) + hh * Dc + d] = acc;
    else             ws[OFF_VWOHC + hh * Dc + d] = acc;
  }
  if (r == Bc * Tc) {
    float qa = bq[d];
    for (int c2 = 0; c2 < Dc; ++c2) qa = fmaf(hsm[c2], Wq[c2 * Dc + d], qa);
    ws[OFF_QCLS + d] = qa;
  }
}

// ---- K2: per (b,i): scores (fused) + softmax per length + x0 + ln2(x0). ----
__global__ __launch_bounds__(256) void k_attn(
    const float* __restrict__ cls, const float* __restrict__ bo,
    const float* __restrict__ g2, const float* __restrict__ b2,
    float* __restrict__ ws) {
  const int wg = blockIdx.x;  // b*T + i
  const int i = wg & (Tc - 1);
  const int d = threadIdx.x;
  const int lmax = imin(Tc - i, Lc);
  __shared__ float sv[Hc][Lc + 1];
  __shared__ float aP[Lc][Hc][Lc + 1];
  __shared__ __align__(16) float redA[Lc][4];
  __shared__ __align__(16) float redB[Lc][4];

  // scores: wave = head, lane = c in [0,64)
  const int hh = d >> 6, lane = d & 63;
  {
    const float qv = ws[OFF_QCLS + hh * DH + lane];
    for (int j = 0; j <= Lc; ++j) {
      float p = 0.f;
      if (j == 0) p = qv * ws[OFF_KCLS + hh * DH + lane];
      else if (j - 1 < lmax) p = qv * ws[OFF_K + (wg + j - 1) * Dc + hh * DH + lane];
#pragma unroll
      for (int off = 32; off; off >>= 1) p += __shfl_down(p, off, 64);
      if (lane == 0) sv[hh][j] = p * SCALE;
    }
  }
  __syncthreads();

  if (d < Lc * Hc) {
    const int l = (d >> 2) + 1, h4 = d & 3;
    if (l <= lmax) {
      float mx = -1e30f;
      for (int j = 0; j <= l; ++j) mx = fmaxf(mx, sv[h4][j]);
      float den = 0.f;
      for (int j = 0; j <= l; ++j) den += expf(sv[h4][j] - mx);
      const float inv = 1.f / den;
      for (int j = 0; j <= l; ++j) aP[l - 1][h4][j] = expf(sv[h4][j] - mx) * inv;
    }
  }
  __syncthreads();

  float x0v[Lc];
  const float base = cls[d] + bo[d];
#pragma unroll
  for (int l = 0; l < Lc; ++l) x0v[l] = base;
  for (int j = 0; j <= lmax; ++j) {
    const float* vw = (j == 0) ? (ws + OFF_VWOHC)
                               : (ws + OFF_VWOH + (wg + j - 1) * (Hc * Dc));
    for (int h4 = 0; h4 < Hc; ++h4) {
      const float w = vw[h4 * Dc + d];
      const int lstart = (j == 0) ? 1 : j;
      for (int l = lstart; l <= lmax; ++l) x0v[l - 1] = fmaf(aP[l - 1][h4][j], w, x0v[l - 1]);
    }
  }

  // batched LN over the 8 candidate rows: 2 reduction rounds, 2 barriers
#pragma unroll
  for (int l = 0; l < Lc; ++l) {
    float p = x0v[l];
#pragma unroll
    for (int off = 32; off; off >>= 1) p += __shfl_down(p, off, 64);
    if (lane == 0) redA[l][hh] = p;
  }
  __syncthreads();
  float mean[Lc];
#pragma unroll
  for (int l = 0; l < Lc; ++l) {
    const float4 s4 = *(const float4*)redA[l];
    mean[l] = (s4.x + s4.y + s4.z + s4.w) * (1.f / Dc);
  }
#pragma unroll
  for (int l = 0; l < Lc; ++l) {
    const float cv = x0v[l] - mean[l];
    float p = cv * cv;
#pragma unroll
    for (int off = 32; off; off >>= 1) p += __shfl_down(p, off, 64);
    if (lane == 0) redB[l][hh] = p;
  }
  __syncthreads();

  const float g2d = g2[d], b2d = b2[d];
  for (int l = 1; l <= lmax; ++l) {
    const float4 s4 = *(const float4*)redB[l - 1];
    const float var = (s4.x + s4.y + s4.z + s4.w) * (1.f / Dc);
    const float rstd = 1.f / sqrtf(var + EPS);
    const float h2 = (x0v[l - 1] - mean[l - 1]) * rstd * g2d + b2d;
    const int rowc = wg * Lc + l - 1;
    ws[OFF_X0 + rowc * Dc + d] = x0v[l - 1];
    ws[OFF_H2 + rowc * Dc + d] = h2;
  }
  for (int l = lmax + 1; l <= Lc; ++l) {
    const int rowc = wg * Lc + l - 1;
    ws[OFF_X0 + rowc * Dc + d] = 0.f;
    ws[OFF_H2 + rowc * Dc + d] = 0.f;
  }
}

// ---- K3: fused FFN GEMM pair, wave-independent. ----
// Grid: 512 = 128 m-tiles(16 rows) x 4 F-quarters(512). 256 threads.
// Wave mg owns rows mg*4..+4 end-to-end: stages its h2 rows, computes
// T = relu(h2@W1q) into its ts rows, then U_q = T@W2q over full K=512.
// No __syncthreads at all. Per-lane f-cols = two float4 groups (lane*4, 256+lane*4)
// so every LDS access is stride-16B (conflict-free) or wave-uniform broadcast.
__global__ __launch_bounds__(256) void k_ffn(
    const float* __restrict__ W1, const float* __restrict__ b1f,
    const float* __restrict__ W2, float* __restrict__ ws) {
  const int mtile = blockIdx.x >> 2;
  const int q = blockIdx.x & 3;
  const int r0 = mtile * 16;
  const int tid = threadIdx.x;
  __shared__ float h2s[16][Dc];   // 16 KB
  __shared__ float ts[16][512];   // 32 KB

  // stage h2: wave mg loads exactly rows mg*4..mg*4+3 (tid>>4 = row)
  {
    const int row = tid >> 4, c0 = (tid & 15) * 16;
    const float* src = ws + OFF_H2 + (r0 + row) * Dc + c0;
#pragma unroll
    for (int j = 0; j < 4; ++j)
      *(float4*)&h2s[row][c0 + 4 * j] = *(const float4*)&src[4 * j];
  }

  const int mg = tid >> 6;        // wave id -> rows mg*4..+4
  const int lane = tid & 63;
  const int fA = q * 512 + lane * 4;   // global f, group A
  const int fB = fA + 256;             // global f, group B

  // ---- phase 1: T = relu(h2 @ W1q + b1f) ----
  float t[4][8];
  {
    const float4 bA = *(const float4*)&b1f[fA];
    const float4 bB = *(const float4*)&b1f[fB];
#pragma unroll
    for (int r = 0; r < 4; ++r) {
      t[r][0] = bA.x; t[r][1] = bA.y; t[r][2] = bA.z; t[r][3] = bA.w;
      t[r][4] = bB.x; t[r][5] = bB.y; t[r][6] = bB.z; t[r][7] = bB.w;
    }
  }
  for (int c = 0; c < Dc; c += 4) {
    float4 wA[4], wB[4];
#pragma unroll
    for (int k = 0; k < 4; ++k) {
      wA[k] = *(const float4*)&W1[(c + k) * Fc + fA];
      wB[k] = *(const float4*)&W1[(c + k) * Fc + fB];
    }
#pragma unroll
    for (int r = 0; r < 4; ++r) {
      const float4 h = *(const float4*)&h2s[mg * 4 + r][c];
      const float hv[4] = {h.x, h.y, h.z, h.w};
#pragma unroll
      for (int k = 0; k < 4; ++k) {
        t[r][0] = fmaf(hv[k], wA[k].x, t[r][0]);
        t[r][1] = fmaf(hv[k], wA[k].y, t[r][1]);
        t[r][2] = fmaf(hv[k], wA[k].z, t[r][2]);
        t[r][3] = fmaf(hv[k], wA[k].w, t[r][3]);
        t[r][4] = fmaf(hv[k], wB[k].x, t[r][4]);
        t[r][5] = fmaf(hv[k], wB[k].y, t[r][5]);
        t[r][6] = fmaf(hv[k], wB[k].z, t[r][6]);
        t[r][7] = fmaf(hv[k], wB[k].w, t[r][7]);
      }
    }
  }
#pragma unroll
  for (int r = 0; r < 4; ++r) {
    float4 vA, vB;
    vA.x = fmaxf(t[r][0], 0.f); vA.y = fmaxf(t[r][1], 0.f);
    vA.z = fmaxf(t[r][2], 0.f); vA.w = fmaxf(t[r][3], 0.f);
    vB.x = fmaxf(t[r][4], 0.f); vB.y = fmaxf(t[r][5], 0.f);
    vB.z = fmaxf(t[r][6], 0.f); vB.w = fmaxf(t[r][7], 0.f);
    *(float4*)&ts[mg * 4 + r][lane * 4] = vA;
    *(float4*)&ts[mg * 4 + r][256 + lane * 4] = vB;
  }
  // no barrier: each wave reads only its own ts rows below

  // ---- phase 2: U_q = T @ W2q ----
  const int d4 = lane * 4;
  float u[4][4];
#pragma unroll
  for (int r = 0; r < 4; ++r) { u[r][0] = 0.f; u[r][1] = 0.f; u[r][2] = 0.f; u[r][3] = 0.f; }
  for (int k = 0; k < 512; k += 4) {
    float4 wv[4];
#pragma unroll
    for (int kk = 0; kk < 4; ++kk)
      wv[kk] = *(const float4*)&W2[(q * 512 + k + kk) * Dc + d4];
#pragma unroll
    for (int r = 0; r < 4; ++r) {
      const float4 h = *(const float4*)&ts[mg * 4 + r][k];
      const float hv[4] = {h.x, h.y, h.z, h.w};
#pragma unroll
      for (int kk = 0; kk < 4; ++kk) {
        u[r][0] = fmaf(hv[kk], wv[kk].x, u[r][0]);
        u[r][1] = fmaf(hv[kk], wv[kk].y, u[r][1]);
        u[r][2] = fmaf(hv[kk], wv[kk].z, u[r][2]);
        u[r][3] = fmaf(hv[kk], wv[kk].w, u[r][3]);
      }
    }
  }
  float* up = ws + OFF_UP + q * SLAB;
#pragma unroll
  for (int r = 0; r < 4; ++r) {
    float4 v; v.x = u[r][0]; v.y = u[r][1]; v.z = u[r][2]; v.w = u[r][3];
    *(float4*)&up[(r0 + mg * 4 + r) * Dc + d4] = v;
  }
}

// ---- K4: enc = x0 + Σ up_q + b2f (in place over X0); z = relu(enc@We1+be1)@We2 + be2 ----
__global__ __launch_bounds__(256) void k_encz(
    const float* __restrict__ We1, const float* __restrict__ be1,
    const float* __restrict__ We2, const float* __restrict__ be2,
    const float* __restrict__ b2f, float* __restrict__ ws) {
  const int r0 = blockIdx.x * 8;
  const int f = threadIdx.x;
  __shared__ float encs[8][Dc];
  __shared__ __align__(16) float red[8][4];
  const float bb = b2f[f];
#pragma unroll
  for (int r = 0; r < 8; ++r) {
    const int row = r0 + r;
    const float e = ws[OFF_X0 + row * Dc + f] +
                    ws[OFF_UP + 0 * SLAB + row * Dc + f] +
                    ws[OFF_UP + 1 * SLAB + row * Dc + f] +
                    ws[OFF_UP + 2 * SLAB + row * Dc + f] +
                    ws[OFF_UP + 3 * SLAB + row * Dc + f] + bb;
    ws[OFF_ENC + row * Dc + f] = e;  // in-place over X0
    encs[r][f] = e;
  }
  __syncthreads();

  float g[8];
  const float be1f = be1[f];
#pragma unroll
  for (int r = 0; r < 8; ++r) g[r] = be1f;
  for (int c = 0; c < Dc; ++c) {
    const float w = We1[c * Dc + f];
#pragma unroll
    for (int r = 0; r < 8; ++r) g[r] = fmaf(encs[r][c], w, g[r]);
  }
  const float w2 = We2[f];
  const int lane = f & 63, wv = f >> 6;
#pragma unroll
  for (int r = 0; r < 8; ++r) {
    float p = fmaxf(g[r], 0.f) * w2;
#pragma unroll
    for (int off = 32; off; off >>= 1) p += __shfl_down(p, off, 64);
    if (lane == 0) red[r][wv] = p;
  }
  __syncthreads();
  if (f < 8) {
    const float4 s4 = *(const float4*)red[f];
    ws[OFF_Z + r0 + f] = s4.x + s4.y + s4.z + s4.w + be2[0];
  }
}

// ---- K5: select lstar (fused) + sequential walk via wave shuffles + emit ----
__global__ __launch_bounds__(256) void k_emit(float* __restrict__ ws, float* __restrict__ out) {
  const int b = blockIdx.x;
  const int tid = threadIdx.x;
  __shared__ int lst[Tc];
  __shared__ int path[Tc];
  __shared__ int cnt_s;
  if (tid < Tc) {
    const int i = tid;
    const int lmax = imin(Tc - i, Lc);
    const float* z = ws + OFF_Z + (b * Tc + i) * Lc;
    int ls = lmax;
    for (int l = 1; l <= lmax; ++l) {
      if (z[l - 1] > 0.f) { ls = l; break; }
    }
    lst[tid] = ls;
  }
  __syncthreads();
  if (tid < 64) {  // wave 0: walk via register shuffles (low-latency chain)
    const int a0 = lst[tid], a1 = lst[64 + tid];
    int cur = 0, s = 0;
    while (cur < Tc) {
      const int l = (cur < 64) ? __shfl(a0, cur, 64) : __shfl(a1, cur - 64, 64);
      if (tid == 0) path[s] = cur * Lc + l - 1;
      ++s;
      cur += l;
    }
    if (tid == 0) cnt_s = s;
  }
  __syncthreads();
  const int c = cnt_s;
  for (int s0 = 0; s0 < Tc; s0 += 8) {
    float v[8];
#pragma unroll
    for (int k = 0; k < 8; ++k) {
      const int s = s0 + k;
      v[k] = (s < c) ? ws[OFF_ENC + (b * Tc * Lc + path[s]) * Dc + tid] : 0.f;
    }
#pragma unroll
    for (int k = 0; k < 8; ++k) out[(b * Tc + s0 + k) * Dc + tid] = v[k];
  }
  if (tid == 0) out[Bc * Tc * Dc + b] = (float)c;
}

extern "C" void kernel_launch(void* const* d_in, const int* in_sizes, int n_in,
                              void* d_out, int out_size, void* d_ws, size_t ws_size,
                              hipStream_t stream) {
  const float* frames = (const float*)d_in[0];
  const float* cls    = (const float*)d_in[1];
  const float* Wq     = (const float*)d_in[2];
  const float* bq     = (const float*)d_in[3];
  const float* Wk     = (const float*)d_in[4];
  const float* bk     = (const float*)d_in[5];
  const float* Wv     = (const float*)d_in[6];
  const float* bv     = (const float*)d_in[7];
  const float* Wo     = (const float*)d_in[8];
  const float* bo     = (const float*)d_in[9];
  const float* g1     = (const float*)d_in[10];
  const float* b1     = (const float*)d_in[11];
  const float* g2     = (const float*)d_in[12];
  const float* b2     = (const float*)d_in[13];
  const float* W1     = (const float*)d_in[14];
  const float* b1f    = (const float*)d_in[15];
  const float* W2     = (const float*)d_in[16];
  const float* b2f    = (const float*)d_in[17];
  const float* We1    = (const float*)d_in[18];
  const float* be1    = (const float*)d_in[19];
  const float* We2    = (const float*)d_in[20];
  const float* be2    = (const float*)d_in[21];
  float* ws = (float*)d_ws;
  float* out = (float*)d_out;

  k_prep<<<Bc * Tc + 1, 256, 0, stream>>>(frames, cls, Wq, bq, Wk, bk, Wv, bv, Wo, g1, b1, ws);
  k_attn<<<Bc * Tc, 256, 0, stream>>>(cls, bo, g2, b2, ws);
  k_ffn<<<512, 256, 0, stream>>>(W1, b1f, W2, ws);
  k_encz<<<NROWS / 8, 256, 0, stream>>>(We1, be1, We2, be2, b2f, ws);
  k_emit<<<Bc, 256, 0, stream>>>(ws, out);
}

// Round 4
// 253.130 us; speedup vs baseline: 3.3217x; 1.0029x over previous
//
#include <hip/hip_runtime.h>

#define DEV __device__ __forceinline__

constexpr int Bc = 2, Tc = 128, Dc = 256, Lc = 8, Hc = 4, DH = 64, Fc = 2048;
constexpr float EPS = 1e-5f, SCALE = 0.125f;  // 1/sqrt(64)
constexpr int NROWS = Bc * Tc * Lc;           // 2048 candidate rows
constexpr int SLAB = NROWS * Dc;              // 524288 floats

// ---- workspace layout (float offsets) ----
constexpr int OFF_K     = 0;                      // B*T*D frame keys
constexpr int OFF_VWOH  = OFF_K + Bc * Tc * Dc;   // B*T*H*D per-head v@Wo partials
constexpr int OFF_QCLS  = OFF_VWOH + Bc * Tc * Hc * Dc;
constexpr int OFF_KCLS  = OFF_QCLS + Dc;
constexpr int OFF_VWOHC = OFF_KCLS + Dc;          // H*D
constexpr int OFF_X0    = OFF_VWOHC + Hc * Dc;    // B*T*L*D attn residual; k_ffn overwrites as ENC
constexpr int OFF_ENC   = OFF_X0;
constexpr int OFF_H2    = OFF_X0 + SLAB;          // B*T*L*D ln2(x0)
constexpr int OFF_Z     = OFF_H2 + SLAB;          // B*T*L eoc logits
// total ~1.45M floats ~= 5.8 MB

DEV int imin(int a, int b) { return a < b ? a : b; }

// block = 256 threads (4 waves). red must be shared float[4].
DEV float blockReduceSum(float v, float* red) {
#pragma unroll
  for (int off = 32; off; off >>= 1) v += __shfl_down(v, off, 64);
  const int lane = threadIdx.x & 63;
  const int w = threadIdx.x >> 6;
  __syncthreads();  // protect red from previous use
  if (lane == 0) red[w] = v;
  __syncthreads();
  return red[0] + red[1] + red[2] + red[3];
}

// ---- K1: one row per block. LN1 + k/v projections + per-head v@Wo; q for CLS row. ----
__global__ __launch_bounds__(256) void k_prep(
    const float* __restrict__ frames, const float* __restrict__ cls,
    const float* __restrict__ Wq, const float* __restrict__ bq,
    const float* __restrict__ Wk, const float* __restrict__ bk,
    const float* __restrict__ Wv, const float* __restrict__ bv,
    const float* __restrict__ Wo,
    const float* __restrict__ g1, const float* __restrict__ b1,
    float* __restrict__ ws) {
  __shared__ float hsm[Dc];
  __shared__ float vsm[Dc];
  __shared__ float red[4];
  const int d = threadIdx.x;
  const int r = blockIdx.x;  // 0..B*T-1 frames, B*T = cls

  const float x = (r < Bc * Tc) ? frames[r * Dc + d] : cls[d];
  const float s = blockReduceSum(x, red);
  const float m = s * (1.0f / Dc);
  const float c = x - m;
  const float var = blockReduceSum(c * c, red) * (1.0f / Dc);
  hsm[d] = c * (1.0f / sqrtf(var + EPS)) * g1[d] + b1[d];
  __syncthreads();

  float ka = bk[d], va = bv[d];
  for (int c2 = 0; c2 < Dc; ++c2) {
    const float h = hsm[c2];
    ka = fmaf(h, Wk[c2 * Dc + d], ka);
    va = fmaf(h, Wv[c2 * Dc + d], va);
  }
  if (r < Bc * Tc) ws[OFF_K + r * Dc + d] = ka;
  else             ws[OFF_KCLS + d] = ka;
  vsm[d] = va;
  __syncthreads();

#pragma unroll
  for (int hh = 0; hh < Hc; ++hh) {
    float acc = 0.f;
    for (int c2 = 0; c2 < DH; ++c2)
      acc = fmaf(vsm[hh * DH + c2], Wo[(hh * DH + c2) * Dc + d], acc);
    if (r < Bc * Tc) ws[OFF_VWOH + r * (Hc * Dc) + hh * Dc + d] = acc;
    else             ws[OFF_VWOHC + hh * Dc + d] = acc;
  }
  if (r == Bc * Tc) {
    float qa = bq[d];
    for (int c2 = 0; c2 < Dc; ++c2) qa = fmaf(hsm[c2], Wq[c2 * Dc + d], qa);
    ws[OFF_QCLS + d] = qa;
  }
}

// ---- K2: per (b,i): scores (fused) + softmax per length + x0 + ln2(x0). ----
__global__ __launch_bounds__(256) void k_attn(
    const float* __restrict__ cls, const float* __restrict__ bo,
    const float* __restrict__ g2, const float* __restrict__ b2,
    float* __restrict__ ws) {
  const int wg = blockIdx.x;  // b*T + i
  const int i = wg & (Tc - 1);
  const int d = threadIdx.x;
  const int lmax = imin(Tc - i, Lc);
  __shared__ float sv[Hc][Lc + 1];
  __shared__ float aP[Lc][Hc][Lc + 1];
  __shared__ __align__(16) float redA[Lc][4];
  __shared__ __align__(16) float redB[Lc][4];

  // scores: wave = head, lane = c in [0,64)
  const int hh = d >> 6, lane = d & 63;
  {
    const float qv = ws[OFF_QCLS + hh * DH + lane];
    for (int j = 0; j <= Lc; ++j) {
      float p = 0.f;
      if (j == 0) p = qv * ws[OFF_KCLS + hh * DH + lane];
      else if (j - 1 < lmax) p = qv * ws[OFF_K + (wg + j - 1) * Dc + hh * DH + lane];
#pragma unroll
      for (int off = 32; off; off >>= 1) p += __shfl_down(p, off, 64);
      if (lane == 0) sv[hh][j] = p * SCALE;
    }
  }
  __syncthreads();

  if (d < Lc * Hc) {
    const int l = (d >> 2) + 1, h4 = d & 3;
    if (l <= lmax) {
      float mx = -1e30f;
      for (int j = 0; j <= l; ++j) mx = fmaxf(mx, sv[h4][j]);
      float den = 0.f;
      for (int j = 0; j <= l; ++j) den += expf(sv[h4][j] - mx);
      const float inv = 1.f / den;
      for (int j = 0; j <= l; ++j) aP[l - 1][h4][j] = expf(sv[h4][j] - mx) * inv;
    }
  }
  __syncthreads();

  float x0v[Lc];
  const float base = cls[d] + bo[d];
#pragma unroll
  for (int l = 0; l < Lc; ++l) x0v[l] = base;
  for (int j = 0; j <= lmax; ++j) {
    const float* vw = (j == 0) ? (ws + OFF_VWOHC)
                               : (ws + OFF_VWOH + (wg + j - 1) * (Hc * Dc));
    for (int h4 = 0; h4 < Hc; ++h4) {
      const float w = vw[h4 * Dc + d];
      const int lstart = (j == 0) ? 1 : j;
      for (int l = lstart; l <= lmax; ++l) x0v[l - 1] = fmaf(aP[l - 1][h4][j], w, x0v[l - 1]);
    }
  }

  // batched LN over the 8 candidate rows: 2 reduction rounds, 2 barriers
#pragma unroll
  for (int l = 0; l < Lc; ++l) {
    float p = x0v[l];
#pragma unroll
    for (int off = 32; off; off >>= 1) p += __shfl_down(p, off, 64);
    if (lane == 0) redA[l][hh] = p;
  }
  __syncthreads();
  float mean[Lc];
#pragma unroll
  for (int l = 0; l < Lc; ++l) {
    const float4 s4 = *(const float4*)redA[l];
    mean[l] = (s4.x + s4.y + s4.z + s4.w) * (1.f / Dc);
  }
#pragma unroll
  for (int l = 0; l < Lc; ++l) {
    const float cv = x0v[l] - mean[l];
    float p = cv * cv;
#pragma unroll
    for (int off = 32; off; off >>= 1) p += __shfl_down(p, off, 64);
    if (lane == 0) redB[l][hh] = p;
  }
  __syncthreads();

  const float g2d = g2[d], b2d = b2[d];
  for (int l = 1; l <= lmax; ++l) {
    const float4 s4 = *(const float4*)redB[l - 1];
    const float var = (s4.x + s4.y + s4.z + s4.w) * (1.f / Dc);
    const float rstd = 1.f / sqrtf(var + EPS);
    const float h2 = (x0v[l - 1] - mean[l - 1]) * rstd * g2d + b2d;
    const int rowc = wg * Lc + l - 1;
    ws[OFF_X0 + rowc * Dc + d] = x0v[l - 1];
    ws[OFF_H2 + rowc * Dc + d] = h2;
  }
  for (int l = lmax + 1; l <= Lc; ++l) {
    const int rowc = wg * Lc + l - 1;
    ws[OFF_X0 + rowc * Dc + d] = 0.f;
    ws[OFF_H2 + rowc * Dc + d] = 0.f;
  }
}

// ---- K3: MEGA-FUSED FFN: U = relu(h2@W1+b1)@W2, enc = x0+U+b2f, z = relu(enc@We1+be1)@We2+be2.
// 256 blocks x 512 threads (8 waves/CU). Block owns 8 rows x full F=2048 ->
// W1+W2 read exactly once per block (4MB x 256 = 1GB L2). F split in TIME
// (two 1024-halves through a 32KB ts buffer). Phase2: 8-wave K-split, each wave
// a disjoint 128-slice per half; deterministic 2-round LDS reduce (redb aliases
// dead ts). All LDS traffic is broadcast / stride-16B/8B -> no bank conflicts.
__global__ __launch_bounds__(512) void k_ffn(
    const float* __restrict__ W1, const float* __restrict__ b1f,
    const float* __restrict__ W2, const float* __restrict__ b2f,
    const float* __restrict__ We1, const float* __restrict__ be1,
    const float* __restrict__ We2, const float* __restrict__ be2,
    float* __restrict__ ws) {
  const int r0 = blockIdx.x * 8;
  const int tid = threadIdx.x;
  const int wv = tid >> 6, lane = tid & 63;
  __shared__ float ts[8][1024];    // 32KB; aliased as redb[4][8][256] after phase 2
  __shared__ float h2s[8][256];    // 8KB
  __shared__ float encs[8][256];   // 8KB
  __shared__ float zred[8][4];

  // stage h2: wave = row, lane covers 256 cols as float4
  *(float4*)&h2s[wv][lane * 4] =
      *(const float4*)&ws[OFF_H2 + (r0 + wv) * Dc + lane * 4];
  __syncthreads();

  float u[8][4];
#pragma unroll
  for (int r = 0; r < 8; ++r) { u[r][0] = 0.f; u[r][1] = 0.f; u[r][2] = 0.f; u[r][3] = 0.f; }

  for (int half = 0; half < 2; ++half) {
    // ---- phase 1: T(half) = relu(h2 @ W1[:, half] + b1f) ----
    const int fg = half * 1024 + tid * 2;  // thread owns 2 f-cols of this half
    float t[8][2];
    {
      const float2 bb = *(const float2*)&b1f[fg];
#pragma unroll
      for (int r = 0; r < 8; ++r) { t[r][0] = bb.x; t[r][1] = bb.y; }
    }
    for (int c = 0; c < Dc; c += 4) {
      float2 wv1[4];
#pragma unroll
      for (int k = 0; k < 4; ++k) wv1[k] = *(const float2*)&W1[(c + k) * Fc + fg];
#pragma unroll
      for (int r = 0; r < 8; ++r) {
        const float4 h = *(const float4*)&h2s[r][c];
        const float hv[4] = {h.x, h.y, h.z, h.w};
#pragma unroll
        for (int k = 0; k < 4; ++k) {
          t[r][0] = fmaf(hv[k], wv1[k].x, t[r][0]);
          t[r][1] = fmaf(hv[k], wv1[k].y, t[r][1]);
        }
      }
    }
    __syncthreads();  // half=1: previous phase-2 ts reads done; half=0: cheap no-op sync
#pragma unroll
    for (int r = 0; r < 8; ++r) {
      float2 v; v.x = fmaxf(t[r][0], 0.f); v.y = fmaxf(t[r][1], 0.f);
      *(float2*)&ts[r][tid * 2] = v;
    }
    __syncthreads();

    // ---- phase 2: u += T(half) @ W2[half, :]; wave wv owns k-slice of 128 ----
    for (int kk = 0; kk < 128; kk += 4) {
      const int kl = wv * 128 + kk;          // col in ts (local to half)
      const int kg = half * 1024 + kl;       // global W2 row
      float4 wv2[4];
#pragma unroll
      for (int k = 0; k < 4; ++k)
        wv2[k] = *(const float4*)&W2[(kg + k) * Dc + lane * 4];
#pragma unroll
      for (int r = 0; r < 8; ++r) {
        const float4 h = *(const float4*)&ts[r][kl];
        const float hv[4] = {h.x, h.y, h.z, h.w};
#pragma unroll
        for (int k = 0; k < 4; ++k) {
          u[r][0] = fmaf(hv[k], wv2[k].x, u[r][0]);
          u[r][1] = fmaf(hv[k], wv2[k].y, u[r][1]);
          u[r][2] = fmaf(hv[k], wv2[k].z, u[r][2]);
          u[r][3] = fmaf(hv[k], wv2[k].w, u[r][3]);
        }
      }
    }
    __syncthreads();  // all ts reads for this half done before overwrite / redb
  }

  // ---- deterministic 2-round cross-wave reduce over redb (aliases ts) ----
  float* redb = &ts[0][0];  // [4][8][256]
  if (wv < 4) {
#pragma unroll
    for (int r = 0; r < 8; ++r) {
      float4 v; v.x = u[r][0]; v.y = u[r][1]; v.z = u[r][2]; v.w = u[r][3];
      *(float4*)&redb[(wv * 8 + r) * 256 + lane * 4] = v;
    }
  }
  __syncthreads();
  if (wv >= 4) {
#pragma unroll
    for (int r = 0; r < 8; ++r) {
      float4 p = *(float4*)&redb[((wv - 4) * 8 + r) * 256 + lane * 4];
      p.x += u[r][0]; p.y += u[r][1]; p.z += u[r][2]; p.w += u[r][3];
      *(float4*)&redb[((wv - 4) * 8 + r) * 256 + lane * 4] = p;
    }
  }
  __syncthreads();

  // ---- enc = x0 + U + b2f; store to global (over X0) + LDS ----
  {
    const int r = wv, d4 = lane * 4;
    float4 s = *(const float4*)&redb[(0 * 8 + r) * 256 + d4];
    const float4 s1 = *(const float4*)&redb[(1 * 8 + r) * 256 + d4];
    const float4 s2 = *(const float4*)&redb[(2 * 8 + r) * 256 + d4];
    const float4 s3 = *(const float4*)&redb[(3 * 8 + r) * 256 + d4];
    s.x = ((s.x + s1.x) + s2.x) + s3.x;
    s.y = ((s.y + s1.y) + s2.y) + s3.y;
    s.z = ((s.z + s1.z) + s2.z) + s3.z;
    s.w = ((s.w + s1.w) + s2.w) + s3.w;
    const float4 x0 = *(const float4*)&ws[OFF_X0 + (r0 + r) * Dc + d4];
    const float4 bb = *(const float4*)&b2f[d4];
    float4 e;
    e.x = (x0.x + s.x) + bb.x; e.y = (x0.y + s.y) + bb.y;
    e.z = (x0.z + s.z) + bb.z; e.w = (x0.w + s.w) + bb.w;
    *(float4*)&ws[OFF_ENC + (r0 + r) * Dc + d4] = e;
    *(float4*)&encs[r][d4] = e;
  }
  __syncthreads();

  // ---- phase 3: z = relu(enc@We1+be1)@We2 + be2 ----
  {
    const int f = tid & 255;      // waves 0-3: rows 0-3; waves 4-7: rows 4-7
    const int rh = tid >> 8;
    float g[4];
    const float be1f = be1[f];
#pragma unroll
    for (int rr = 0; rr < 4; ++rr) g[rr] = be1f;
    for (int c = 0; c < Dc; ++c) {
      const float w = We1[c * Dc + f];
#pragma unroll
      for (int rr = 0; rr < 4; ++rr) g[rr] = fmaf(encs[rh * 4 + rr][c], w, g[rr]);
    }
    const float w2 = We2[f];
#pragma unroll
    for (int rr = 0; rr < 4; ++rr) {
      float p = fmaxf(g[rr], 0.f) * w2;
#pragma unroll
      for (int off = 32; off; off >>= 1) p += __shfl_down(p, off, 64);
      if (lane == 0) zred[wv][rr] = p;
    }
  }
  __syncthreads();
  if (tid < 8) {
    const int r = tid;
    const int wb = (r < 4) ? 0 : 4;
    const int rl = r & 3;
    const float z = ((zred[wb + 0][rl] + zred[wb + 1][rl]) + zred[wb + 2][rl]) +
                    zred[wb + 3][rl];
    ws[OFF_Z + blockIdx.x * 8 + r] = z + be2[0];
  }
}

// ---- K4: select lstar (fused) + sequential walk via wave shuffles + emit ----
__global__ __launch_bounds__(256) void k_emit(float* __restrict__ ws, float* __restrict__ out) {
  const int b = blockIdx.x;
  const int tid = threadIdx.x;
  __shared__ int lst[Tc];
  __shared__ int path[Tc];
  __shared__ int cnt_s;
  if (tid < Tc) {
    const int i = tid;
    const int lmax = imin(Tc - i, Lc);
    const float* z = ws + OFF_Z + (b * Tc + i) * Lc;
    int ls = lmax;
    for (int l = 1; l <= lmax; ++l) {
      if (z[l - 1] > 0.f) { ls = l; break; }
    }
    lst[tid] = ls;
  }
  __syncthreads();
  if (tid < 64) {  // wave 0: walk via register shuffles (low-latency chain)
    const int a0 = lst[tid], a1 = lst[64 + tid];
    int cur = 0, s = 0;
    while (cur < Tc) {
      const int l = (cur < 64) ? __shfl(a0, cur, 64) : __shfl(a1, cur - 64, 64);
      if (tid == 0) path[s] = cur * Lc + l - 1;
      ++s;
      cur += l;
    }
    if (tid == 0) cnt_s = s;
  }
  __syncthreads();
  const int c = cnt_s;
  for (int s0 = 0; s0 < Tc; s0 += 8) {
    float v[8];
#pragma unroll
    for (int k = 0; k < 8; ++k) {
      const int s = s0 + k;
      v[k] = (s < c) ? ws[OFF_ENC + (b * Tc * Lc + path[s]) * Dc + tid] : 0.f;
    }
#pragma unroll
    for (int k = 0; k < 8; ++k) out[(b * Tc + s0 + k) * Dc + tid] = v[k];
  }
  if (tid == 0) out[Bc * Tc * Dc + b] = (float)c;
}

extern "C" void kernel_launch(void* const* d_in, const int* in_sizes, int n_in,
                              void* d_out, int out_size, void* d_ws, size_t ws_size,
                              hipStream_t stream) {
  const float* frames = (const float*)d_in[0];
  const float* cls    = (const float*)d_in[1];
  const float* Wq     = (const float*)d_in[2];
  const float* bq     = (const float*)d_in[3];
  const float* Wk     = (const float*)d_in[4];
  const float* bk     = (const float*)d_in[5];
  const float* Wv     = (const float*)d_in[6];
  const float* bv     = (const float*)d_in[7];
  const float* Wo     = (const float*)d_in[8];
  const float* bo     = (const float*)d_in[9];
  const float* g1     = (const float*)d_in[10];
  const float* b1     = (const float*)d_in[11];
  const float* g2     = (const float*)d_in[12];
  const float* b2     = (const float*)d_in[13];
  const float* W1     = (const float*)d_in[14];
  const float* b1f    = (const float*)d_in[15];
  const float* W2     = (const float*)d_in[16];
  const float* b2f    = (const float*)d_in[17];
  const float* We1    = (const float*)d_in[18];
  const float* be1    = (const float*)d_in[19];
  const float* We2    = (const float*)d_in[20];
  const float* be2    = (const float*)d_in[21];
  float* ws = (float*)d_ws;
  float* out = (float*)d_out;

  k_prep<<<Bc * Tc + 1, 256, 0, stream>>>(frames, cls, Wq, bq, Wk, bk, Wv, bv, Wo, g1, b1, ws);
  k_attn<<<Bc * Tc, 256, 0, stream>>>(cls, bo, g2, b2, ws);
  k_ffn<<<NROWS / 8, 512, 0, stream>>>(W1, b1f, W2, b2f, We1, be1, We2, be2, ws);
  k_emit<<<Bc, 256, 0, stream>>>(ws, out);
}

// Round 5
// 243.391 us; speedup vs baseline: 3.4546x; 1.0400x over previous
//
#include <hip/hip_runtime.h>

#define DEV __device__ __forceinline__

constexpr int Bc = 2, Tc = 128, Dc = 256, Lc = 8, Hc = 4, DH = 64, Fc = 2048;
constexpr float EPS = 1e-5f, SCALE = 0.125f;  // 1/sqrt(64)
constexpr int NROWS = Bc * Tc * Lc;           // 2048 candidate rows
constexpr int SLAB = NROWS * Dc;              // 524288 floats

// ---- workspace layout (float offsets) ----
constexpr int OFF_K     = 0;                        // B*T*D frame keys
constexpr int OFF_VWOH  = OFF_K + Bc * Tc * Dc;     // B*T*H*D per-head v@Wo partials
constexpr int OFF_QCLS  = OFF_VWOH + Bc * Tc * Hc * Dc;
constexpr int OFF_KCLS  = OFF_QCLS + Dc;
constexpr int OFF_VWOHC = OFF_KCLS + Dc;            // H*D
constexpr int OFF_ENC   = OFF_VWOHC + Hc * Dc;      // B*T*L*D encoder CLS outputs
constexpr int OFF_Z     = OFF_ENC + SLAB;           // B*T*L eoc logits
// total ~0.86M floats ~= 3.4 MB

DEV int imin(int a, int b) { return a < b ? a : b; }

// block = 256 threads (4 waves). red must be shared float[4].
DEV float blockReduceSum(float v, float* red) {
#pragma unroll
  for (int off = 32; off; off >>= 1) v += __shfl_down(v, off, 64);
  const int lane = threadIdx.x & 63;
  const int w = threadIdx.x >> 6;
  __syncthreads();  // protect red from previous use
  if (lane == 0) red[w] = v;
  __syncthreads();
  return red[0] + red[1] + red[2] + red[3];
}

// ---- K1: one row per block. LN1 + k/v projections + per-head v@Wo; q for CLS row. ----
__global__ __launch_bounds__(256) void k_prep(
    const float* __restrict__ frames, const float* __restrict__ cls,
    const float* __restrict__ Wq, const float* __restrict__ bq,
    const float* __restrict__ Wk, const float* __restrict__ bk,
    const float* __restrict__ Wv, const float* __restrict__ bv,
    const float* __restrict__ Wo,
    const float* __restrict__ g1, const float* __restrict__ b1,
    float* __restrict__ ws) {
  __shared__ float hsm[Dc];
  __shared__ float vsm[Dc];
  __shared__ float red[4];
  const int d = threadIdx.x;
  const int r = blockIdx.x;  // 0..B*T-1 frames, B*T = cls

  const float x = (r < Bc * Tc) ? frames[r * Dc + d] : cls[d];
  const float s = blockReduceSum(x, red);
  const float m = s * (1.0f / Dc);
  const float c = x - m;
  const float var = blockReduceSum(c * c, red) * (1.0f / Dc);
  hsm[d] = c * (1.0f / sqrtf(var + EPS)) * g1[d] + b1[d];
  __syncthreads();

  float ka = bk[d], va = bv[d];
  for (int c2 = 0; c2 < Dc; ++c2) {
    const float h = hsm[c2];
    ka = fmaf(h, Wk[c2 * Dc + d], ka);
    va = fmaf(h, Wv[c2 * Dc + d], va);
  }
  if (r < Bc * Tc) ws[OFF_K + r * Dc + d] = ka;
  else             ws[OFF_KCLS + d] = ka;
  vsm[d] = va;
  __syncthreads();

#pragma unroll
  for (int hh = 0; hh < Hc; ++hh) {
    float acc = 0.f;
    for (int c2 = 0; c2 < DH; ++c2)
      acc = fmaf(vsm[hh * DH + c2], Wo[(hh * DH + c2) * Dc + d], acc);
    if (r < Bc * Tc) ws[OFF_VWOH + r * (Hc * Dc) + hh * Dc + d] = acc;
    else             ws[OFF_VWOHC + hh * Dc + d] = acc;
  }
  if (r == Bc * Tc) {
    float qa = bq[d];
    for (int c2 = 0; c2 < Dc; ++c2) qa = fmaf(hsm[c2], Wq[c2 * Dc + d], qa);
    ws[OFF_QCLS + d] = qa;
  }
}

// ---- K2: FULLY FUSED per (b,i): scores + softmax + x0 + ln2 (in LDS) + FFN + enc + z.
// 256 blocks x 512 threads. The 8 candidate rows of one (b,i) ARE the ffn row-tile,
// so attn->ffn->z has no cross-block dependency: h2/x0 never touch global memory.
// FFN core identical to R4 (F split in time, 8-wave K-split, deterministic reduce).
__global__ __launch_bounds__(512) void k_fused(
    const float* __restrict__ cls, const float* __restrict__ bo,
    const float* __restrict__ g2, const float* __restrict__ b2,
    const float* __restrict__ W1, const float* __restrict__ b1f,
    const float* __restrict__ W2, const float* __restrict__ b2f,
    const float* __restrict__ We1, const float* __restrict__ be1,
    const float* __restrict__ We2, const float* __restrict__ be2,
    float* __restrict__ ws) {
  const int wg = blockIdx.x;  // b*T + i
  const int i = wg & (Tc - 1);
  const int tid = threadIdx.x;
  const int wv = tid >> 6, lane = tid & 63;
  const int lmax = imin(Tc - i, Lc);

  __shared__ float ts[8][1024];    // 32KB; aliased as redb[4][8][256] after phase 2
  __shared__ float h2s[8][256];    // 8KB
  __shared__ float x0s[8][256];    // 8KB
  __shared__ float encs[8][256];   // 8KB
  __shared__ float sv[Hc][Lc + 1];
  __shared__ float aP[Lc][Hc][Lc + 1];
  __shared__ __align__(16) float redA[Lc][4];
  __shared__ __align__(16) float redB[Lc][4];
  __shared__ float zred[8][4];

  // ---- scores: waves 0-3, wave = head ----
  if (tid < 256) {
    const int hh = tid >> 6;
    const float qv = ws[OFF_QCLS + hh * DH + lane];
    for (int j = 0; j <= Lc; ++j) {
      float p = 0.f;
      if (j == 0) p = qv * ws[OFF_KCLS + hh * DH + lane];
      else if (j - 1 < lmax) p = qv * ws[OFF_K + (wg + j - 1) * Dc + hh * DH + lane];
#pragma unroll
      for (int off = 32; off; off >>= 1) p += __shfl_down(p, off, 64);
      if (lane == 0) sv[hh][j] = p * SCALE;
    }
  }
  __syncthreads();

  // ---- softmax per candidate length ----
  if (tid < Lc * Hc) {
    const int l = (tid >> 2) + 1, h4 = tid & 3;
    if (l <= lmax) {
      float mx = -1e30f;
      for (int j = 0; j <= l; ++j) mx = fmaxf(mx, sv[h4][j]);
      float den = 0.f;
      for (int j = 0; j <= l; ++j) den += expf(sv[h4][j] - mx);
      const float inv = 1.f / den;
      for (int j = 0; j <= l; ++j) aP[l - 1][h4][j] = expf(sv[h4][j] - mx) * inv;
    }
  }
  __syncthreads();

  // ---- x0 accumulation + LN round 1 (threads 0-255, d = tid) ----
  float x0v[Lc];
  if (tid < 256) {
    const int d = tid;
    const float base = cls[d] + bo[d];
#pragma unroll
    for (int l = 0; l < Lc; ++l) x0v[l] = base;
    for (int j = 0; j <= lmax; ++j) {
      const float* vwp = (j == 0) ? (ws + OFF_VWOHC)
                                  : (ws + OFF_VWOH + (wg + j - 1) * (Hc * Dc));
      for (int h4 = 0; h4 < Hc; ++h4) {
        const float w = vwp[h4 * Dc + d];
        const int lstart = (j == 0) ? 1 : j;
        for (int l = lstart; l <= lmax; ++l) x0v[l - 1] = fmaf(aP[l - 1][h4][j], w, x0v[l - 1]);
      }
    }
#pragma unroll
    for (int l = 0; l < Lc; ++l) {
      float p = x0v[l];
#pragma unroll
      for (int off = 32; off; off >>= 1) p += __shfl_down(p, off, 64);
      if (lane == 0) redA[l][tid >> 6] = p;
    }
  }
  __syncthreads();

  float mean[Lc];
  if (tid < 256) {
#pragma unroll
    for (int l = 0; l < Lc; ++l) {
      const float4 s4 = *(const float4*)redA[l];
      mean[l] = (s4.x + s4.y + s4.z + s4.w) * (1.f / Dc);
    }
#pragma unroll
    for (int l = 0; l < Lc; ++l) {
      const float cv = x0v[l] - mean[l];
      float p = cv * cv;
#pragma unroll
      for (int off = 32; off; off >>= 1) p += __shfl_down(p, off, 64);
      if (lane == 0) redB[l][tid >> 6] = p;
    }
  }
  __syncthreads();

  if (tid < 256) {
    const int d = tid;
    const float g2d = g2[d], b2d = b2[d];
    for (int l = 1; l <= lmax; ++l) {
      const float4 s4 = *(const float4*)redB[l - 1];
      const float var = (s4.x + s4.y + s4.z + s4.w) * (1.f / Dc);
      const float rstd = 1.f / sqrtf(var + EPS);
      h2s[l - 1][d] = (x0v[l - 1] - mean[l - 1]) * rstd * g2d + b2d;
      x0s[l - 1][d] = x0v[l - 1];
    }
    for (int l = lmax + 1; l <= Lc; ++l) {
      h2s[l - 1][d] = 0.f;
      x0s[l - 1][d] = 0.f;
    }
  }
  __syncthreads();

  // ---- FFN: U = relu(h2@W1+b1f)@W2 (R4 core) ----
  float u[8][4];
#pragma unroll
  for (int r = 0; r < 8; ++r) { u[r][0] = 0.f; u[r][1] = 0.f; u[r][2] = 0.f; u[r][3] = 0.f; }

  for (int half = 0; half < 2; ++half) {
    // phase 1: T(half) = relu(h2 @ W1[:, half] + b1f)
    const int fg = half * 1024 + tid * 2;
    float t[8][2];
    {
      const float2 bb = *(const float2*)&b1f[fg];
#pragma unroll
      for (int r = 0; r < 8; ++r) { t[r][0] = bb.x; t[r][1] = bb.y; }
    }
    for (int c = 0; c < Dc; c += 4) {
      float2 wv1[4];
#pragma unroll
      for (int k = 0; k < 4; ++k) wv1[k] = *(const float2*)&W1[(c + k) * Fc + fg];
#pragma unroll
      for (int r = 0; r < 8; ++r) {
        const float4 h = *(const float4*)&h2s[r][c];
        const float hv[4] = {h.x, h.y, h.z, h.w};
#pragma unroll
        for (int k = 0; k < 4; ++k) {
          t[r][0] = fmaf(hv[k], wv1[k].x, t[r][0]);
          t[r][1] = fmaf(hv[k], wv1[k].y, t[r][1]);
        }
      }
    }
    __syncthreads();  // half=1: previous phase-2 ts reads done
#pragma unroll
    for (int r = 0; r < 8; ++r) {
      float2 v; v.x = fmaxf(t[r][0], 0.f); v.y = fmaxf(t[r][1], 0.f);
      *(float2*)&ts[r][tid * 2] = v;
    }
    __syncthreads();

    // phase 2: u += T(half) @ W2[half, :]; wave wv owns k-slice of 128
    for (int kk = 0; kk < 128; kk += 4) {
      const int kl = wv * 128 + kk;
      const int kg = half * 1024 + kl;
      float4 wv2[4];
#pragma unroll
      for (int k = 0; k < 4; ++k)
        wv2[k] = *(const float4*)&W2[(kg + k) * Dc + lane * 4];
#pragma unroll
      for (int r = 0; r < 8; ++r) {
        const float4 h = *(const float4*)&ts[r][kl];
        const float hv[4] = {h.x, h.y, h.z, h.w};
#pragma unroll
        for (int k = 0; k < 4; ++k) {
          u[r][0] = fmaf(hv[k], wv2[k].x, u[r][0]);
          u[r][1] = fmaf(hv[k], wv2[k].y, u[r][1]);
          u[r][2] = fmaf(hv[k], wv2[k].z, u[r][2]);
          u[r][3] = fmaf(hv[k], wv2[k].w, u[r][3]);
        }
      }
    }
    __syncthreads();  // all ts reads for this half done before overwrite / redb
  }

  // ---- deterministic 2-round cross-wave reduce over redb (aliases ts) ----
  float* redb = &ts[0][0];  // [4][8][256]
  if (wv < 4) {
#pragma unroll
    for (int r = 0; r < 8; ++r) {
      float4 v; v.x = u[r][0]; v.y = u[r][1]; v.z = u[r][2]; v.w = u[r][3];
      *(float4*)&redb[(wv * 8 + r) * 256 + lane * 4] = v;
    }
  }
  __syncthreads();
  if (wv >= 4) {
#pragma unroll
    for (int r = 0; r < 8; ++r) {
      float4 p = *(float4*)&redb[((wv - 4) * 8 + r) * 256 + lane * 4];
      p.x += u[r][0]; p.y += u[r][1]; p.z += u[r][2]; p.w += u[r][3];
      *(float4*)&redb[((wv - 4) * 8 + r) * 256 + lane * 4] = p;
    }
  }
  __syncthreads();

  // ---- enc = x0 + U + b2f; store to global + LDS ----
  {
    const int r = wv, d4 = lane * 4;
    float4 s = *(const float4*)&redb[(0 * 8 + r) * 256 + d4];
    const float4 s1 = *(const float4*)&redb[(1 * 8 + r) * 256 + d4];
    const float4 s2 = *(const float4*)&redb[(2 * 8 + r) * 256 + d4];
    const float4 s3 = *(const float4*)&redb[(3 * 8 + r) * 256 + d4];
    s.x = ((s.x + s1.x) + s2.x) + s3.x;
    s.y = ((s.y + s1.y) + s2.y) + s3.y;
    s.z = ((s.z + s1.z) + s2.z) + s3.z;
    s.w = ((s.w + s1.w) + s2.w) + s3.w;
    const float4 x0 = *(const float4*)&x0s[r][d4];
    const float4 bb = *(const float4*)&b2f[d4];
    float4 e;
    e.x = (x0.x + s.x) + bb.x; e.y = (x0.y + s.y) + bb.y;
    e.z = (x0.z + s.z) + bb.z; e.w = (x0.w + s.w) + bb.w;
    *(float4*)&ws[OFF_ENC + (wg * 8 + r) * Dc + d4] = e;
    *(float4*)&encs[r][d4] = e;
  }
  __syncthreads();

  // ---- z = relu(enc@We1+be1)@We2 + be2 ----
  {
    const int f = tid & 255;  // waves 0-3: rows 0-3; waves 4-7: rows 4-7
    const int rh = tid >> 8;
    float g[4];
    const float be1f = be1[f];
#pragma unroll
    for (int rr = 0; rr < 4; ++rr) g[rr] = be1f;
    for (int c = 0; c < Dc; ++c) {
      const float w = We1[c * Dc + f];
#pragma unroll
      for (int rr = 0; rr < 4; ++rr) g[rr] = fmaf(encs[rh * 4 + rr][c], w, g[rr]);
    }
    const float w2 = We2[f];
#pragma unroll
    for (int rr = 0; rr < 4; ++rr) {
      float p = fmaxf(g[rr], 0.f) * w2;
#pragma unroll
      for (int off = 32; off; off >>= 1) p += __shfl_down(p, off, 64);
      if (lane == 0) zred[wv][rr] = p;
    }
  }
  __syncthreads();
  if (tid < 8) {
    const int r = tid;
    const int wb = (r < 4) ? 0 : 4;
    const int rl = r & 3;
    const float z = ((zred[wb + 0][rl] + zred[wb + 1][rl]) + zred[wb + 2][rl]) +
                    zred[wb + 3][rl];
    ws[OFF_Z + wg * 8 + r] = z + be2[0];
  }
}

// ---- K3: select lstar (fused) + sequential walk via wave shuffles + emit ----
__global__ __launch_bounds__(256) void k_emit(float* __restrict__ ws, float* __restrict__ out) {
  const int b = blockIdx.x;
  const int tid = threadIdx.x;
  __shared__ int lst[Tc];
  __shared__ int path[Tc];
  __shared__ int cnt_s;
  if (tid < Tc) {
    const int i = tid;
    const int lmax = imin(Tc - i, Lc);
    const float* z = ws + OFF_Z + (b * Tc + i) * Lc;
    int ls = lmax;
    for (int l = 1; l <= lmax; ++l) {
      if (z[l - 1] > 0.f) { ls = l; break; }
    }
    lst[tid] = ls;
  }
  __syncthreads();
  if (tid < 64) {  // wave 0: walk via register shuffles (low-latency chain)
    const int a0 = lst[tid], a1 = lst[64 + tid];
    int cur = 0, s = 0;
    while (cur < Tc) {
      const int l = (cur < 64) ? __shfl(a0, cur, 64) : __shfl(a1, cur - 64, 64);
      if (tid == 0) path[s] = cur * Lc + l - 1;
      ++s;
      cur += l;
    }
    if (tid == 0) cnt_s = s;
  }
  __syncthreads();
  const int c = cnt_s;
  for (int s0 = 0; s0 < Tc; s0 += 8) {
    float v[8];
#pragma unroll
    for (int k = 0; k < 8; ++k) {
      const int s = s0 + k;
      v[k] = (s < c) ? ws[OFF_ENC + (b * Tc * Lc + path[s]) * Dc + tid] : 0.f;
    }
#pragma unroll
    for (int k = 0; k < 8; ++k) out[(b * Tc + s0 + k) * Dc + tid] = v[k];
  }
  if (tid == 0) out[Bc * Tc * Dc + b] = (float)c;
}

extern "C" void kernel_launch(void* const* d_in, const int* in_sizes, int n_in,
                              void* d_out, int out_size, void* d_ws, size_t ws_size,
                              hipStream_t stream) {
  const float* frames = (const float*)d_in[0];
  const float* cls    = (const float*)d_in[1];
  const float* Wq     = (const float*)d_in[2];
  const float* bq     = (const float*)d_in[3];
  const float* Wk     = (const float*)d_in[4];
  const float* bk     = (const float*)d_in[5];
  const float* Wv     = (const float*)d_in[6];
  const float* bv     = (const float*)d_in[7];
  const float* Wo     = (const float*)d_in[8];
  const float* bo     = (const float*)d_in[9];
  const float* g1     = (const float*)d_in[10];
  const float* b1     = (const float*)d_in[11];
  const float* g2     = (const float*)d_in[12];
  const float* b2     = (const float*)d_in[13];
  const float* W1     = (const float*)d_in[14];
  const float* b1f    = (const float*)d_in[15];
  const float* W2     = (const float*)d_in[16];
  const float* b2f    = (const float*)d_in[17];
  const float* We1    = (const float*)d_in[18];
  const float* be1    = (const float*)d_in[19];
  const float* We2    = (const float*)d_in[20];
  const float* be2    = (const float*)d_in[21];
  float* ws = (float*)d_ws;
  float* out = (float*)d_out;

  k_prep<<<Bc * Tc + 1, 256, 0, stream>>>(frames, cls, Wq, bq, Wk, bk, Wv, bv, Wo, g1, b1, ws);
  k_fused<<<Bc * Tc, 512, 0, stream>>>(cls, bo, g2, b2, W1, b1f, W2, b2f, We1, be1, We2, be2, ws);
  k_emit<<<Bc, 256, 0, stream>>>(ws, out);
}